// Round 6
// baseline (1880751.172 us; speedup 1.0000x reference)
//
#include <hip/hip_runtime.h>

typedef unsigned short u16;
typedef unsigned u32;
typedef unsigned long long u64;
typedef __bf16 bf16x8 __attribute__((ext_vector_type(8)));
typedef u16 u16x8 __attribute__((ext_vector_type(8)));
typedef u16 u16x4 __attribute__((ext_vector_type(4)));
typedef u32 u32x4 __attribute__((ext_vector_type(4)));
typedef float f32x4 __attribute__((ext_vector_type(4)));

__device__ __forceinline__ u16 f2bf(float f){
    unsigned u = __builtin_bit_cast(unsigned, f);
    u = (u + 0x7fffu + ((u >> 16) & 1u)) >> 16;
    return (u16)u;
}
__device__ __forceinline__ float bf2f(u16 h){
    unsigned u = ((unsigned)h) << 16;
    return __builtin_bit_cast(float, u);
}
__device__ __forceinline__ float sigmoidf_(float x){ return 1.0f / (1.0f + __expf(-x)); }
__device__ __forceinline__ float tanhf_(float x){
    float e = __expf(2.0f * x);
    return 1.0f - 2.0f / (e + 1.0f);
}

// Coherent ops. ic=false: sc0 (L1-bypass, XCD-local L2 is the shared point).
// ic=true: sc0 sc1 (Infinity Cache — cross-XCD safe fallback).
__device__ __forceinline__ u32x4 tload4(const u32* p, bool ic){
    u32x4 r;
    if (ic)
        asm volatile("global_load_dwordx4 %0, %1, off sc0 sc1\n\ts_waitcnt vmcnt(0)"
                     : "=&v"(r) : "v"(p) : "memory");
    else
        asm volatile("global_load_dwordx4 %0, %1, off sc0\n\ts_waitcnt vmcnt(0)"
                     : "=&v"(r) : "v"(p) : "memory");
    return r;
}
__device__ __forceinline__ u32 tload1(const u32* p, bool ic){
    u32 r;
    if (ic)
        asm volatile("global_load_dword %0, %1, off sc0 sc1\n\ts_waitcnt vmcnt(0)"
                     : "=&v"(r) : "v"(p) : "memory");
    else
        asm volatile("global_load_dword %0, %1, off sc0\n\ts_waitcnt vmcnt(0)"
                     : "=&v"(r) : "v"(p) : "memory");
    return r;
}
__device__ __forceinline__ void tstore1(u32* p, u32 v, bool ic){
    if (ic)
        asm volatile("global_store_dword %0, %1, off sc0 sc1" :: "v"(p), "v"(v) : "memory");
    else
        asm volatile("global_store_dword %0, %1, off sc0" :: "v"(p), "v"(v) : "memory");
}

// ---------------------------------------------------------------------------
// Kernel 0: pack Wx transposed gate-interleaved bf16 (pk = 4*hcol+gate);
// zero the handshake words; bump the launch epoch (keys tags+canaries so
// stale cache lines from previous launches/replays can never fake a match).
// ---------------------------------------------------------------------------
__global__ __launch_bounds__(256) void lstm_pack(
    const float* __restrict__ Wgx, const float* __restrict__ Wix,
    const float* __restrict__ Wfx, const float* __restrict__ Wox,
    u16* __restrict__ Wxpt, u32* __restrict__ gready, u32* __restrict__ epochw)
{
    int idx = blockIdx.x * 256 + threadIdx.x;
    if (idx < 512)
        __hip_atomic_store(gready + idx, 0u,
                           __ATOMIC_RELAXED, __HIP_MEMORY_SCOPE_AGENT);
    if (idx == 0)
        __hip_atomic_fetch_add(epochw, 1u,
                               __ATOMIC_RELAXED, __HIP_MEMORY_SCOPE_AGENT);
    const float* W4[4] = {Wgx, Wix, Wfx, Wox};
    if (idx < 1024 * 128){
        int pk = idx >> 7, k = idx & 127;
        int g = pk & 3, h = pk >> 2;
        Wxpt[idx] = f2bf(W4[g][k * 256 + h]);
    }
}

// ---------------------------------------------------------------------------
// Kernel 1: xg GEMM (math proven R2/R4). Dest layout per rec-block:
// xg[blk][t_local][16 rows][128 pk], blk = (b>>4)*8 + (pk>>7).
// Nontemporal stores: don't thrash the L2s carrying the h exchange.
// ---------------------------------------------------------------------------
__global__ __launch_bounds__(256, 2) void lstm_xg(
    const float* __restrict__ x, const u16* __restrict__ Wxpt,
    u16* __restrict__ xg, int ct0, int steps, int mtiles_total)
{
    __shared__ u16 Bt[32768];
    const int tid = threadIdx.x;
    const int n0 = blockIdx.y << 8;

    for (int ii = 0; ii < 16; ++ii){
        int cid = ii * 256 + tid;
        int nn = cid >> 4;
        int kc = (cid & 15) << 3;
        u16x8 v = *(const u16x8*)(Wxpt + (size_t)(n0 + nn) * 128 + kc);
        unsigned byte = (unsigned)(nn << 8) + (unsigned)(kc << 1);
        byte ^= ((nn & 7) << 4);
        *(u16x8*)((char*)Bt + byte) = v;
    }
    __syncthreads();

    const int w = tid >> 6, l = tid & 63;
    const int l15 = l & 15, l4 = l >> 4;

    for (int i = 0; i < 16; ++i){
        int mtile = blockIdx.x * 16 + i;
        if (mtile >= mtiles_total) break;
        int row = (mtile << 6) + (w << 4) + l15;
        int tl = row >> 8;
        int b = row & 255;
        const float* xr = x + ((size_t)b * 1024 + (ct0 + tl)) * 128;

        f32x4 acc[16];
        #pragma unroll
        for (int nt = 0; nt < 16; ++nt) acc[nt] = (f32x4){0.f, 0.f, 0.f, 0.f};

        #pragma unroll
        for (int kf = 0; kf < 4; ++kf){
            int k0 = kf * 32 + l4 * 8;
            f32x4 xa = *(const f32x4*)(xr + k0);
            f32x4 xb = *(const f32x4*)(xr + k0 + 4);
            u16x8 bu;
            bu[0]=f2bf(xa[0]); bu[1]=f2bf(xa[1]); bu[2]=f2bf(xa[2]); bu[3]=f2bf(xa[3]);
            bu[4]=f2bf(xb[0]); bu[5]=f2bf(xb[1]); bu[6]=f2bf(xb[2]); bu[7]=f2bf(xb[3]);
            bf16x8 bfX = __builtin_bit_cast(bf16x8, bu);
            #pragma unroll
            for (int nt = 0; nt < 16; ++nt){
                int nn = (nt << 4) + l15;
                unsigned byte = (unsigned)(nn << 8) + (unsigned)(k0 << 1);
                byte ^= ((nn & 7) << 4);
                u16x8 au = *(const u16x8*)((const char*)Bt + byte);
                bf16x8 afW = __builtin_bit_cast(bf16x8, au);
                acc[nt] = __builtin_amdgcn_mfma_f32_16x16x32_bf16(afW, bfX, acc[nt], 0, 0, 0);
            }
        }
        #pragma unroll
        for (int nt = 0; nt < 16; ++nt){
            u16x4 o;
            o[0]=f2bf(acc[nt][0]); o[1]=f2bf(acc[nt][1]);
            o[2]=f2bf(acc[nt][2]); o[3]=f2bf(acc[nt][3]);
            int pk = n0 + (nt << 4) + (l4 << 2);
            size_t dst = ((size_t)((b >> 4) * 8 + (pk >> 7)) * steps + tl) * 2048
                       + (size_t)(b & 15) * 128 + (pk & 127);
            __builtin_nontemporal_store(o, (u16x4*)(xg + dst));
        }
    }
}

// ---------------------------------------------------------------------------
// Kernel 2: recurrent scan. 128 blocks x 512 thr = 16 groups (16 rows) x 8
// pk-blocks. Group members share bid&7 -> one XCD under round-robin dispatch.
// Purity is PROVEN at runtime via sc0 canaries (keyed by epoch+dispatch+nb):
// impure => peers' canaries invisible => uniform fallback to sc0sc1 (IC).
// Exchange: tagged words (bf16(h)<<16 | (epoch<<10|t)); watchdogs everywhere.
// ---------------------------------------------------------------------------
__global__ __launch_bounds__(512, 1) void lstm_rec(
    const u16* __restrict__ xg,
    const float* __restrict__ Wgh, const float* __restrict__ Wih,
    const float* __restrict__ Wfh, const float* __restrict__ Woh,
    const float* __restrict__ bgx, const float* __restrict__ bgh,
    const float* __restrict__ bix, const float* __restrict__ bih,
    const float* __restrict__ bfx, const float* __restrict__ bfh,
    const float* __restrict__ box, const float* __restrict__ boh,
    u32* __restrict__ h32, u32* __restrict__ canar, u32* __restrict__ gready,
    u32* __restrict__ epochw,
    float* __restrict__ c_ws, float* __restrict__ hT,
    int ct0, int steps, int hsidx)
{
    __shared__ char lds[16896];        // 2 slots x [16 rows][528B] staged h
    __shared__ int shflag;
    __shared__ u32 sh_epoch;
    const int tid = threadIdx.x;
    const int w = tid >> 6, l = tid & 63;
    const int l15 = l & 15, l4 = l >> 4;
    const int bid = blockIdx.x;
    const int g  = ((bid & 7) << 1) | (bid >> 6);   // group 0..15
    const int nb = (bid >> 3) & 7;                  // pk block 0..7
    const int P0 = (nb << 7) + (w << 4);            // wave's packed-col base

    // ---- one-time: Wh^T fragments (hi/lo split) into VGPRs ----
    const float* Wh4[4] = {Wgh, Wih, Wfh, Woh};
    int pkA = P0 + l15;
    const float* Wcol = Wh4[pkA & 3] + (pkA >> 2);
    bf16x8 whi[8], wlo[8];
    #pragma unroll
    for (int kf = 0; kf < 8; ++kf){
        u16x8 hi8, lo8;
        #pragma unroll
        for (int j = 0; j < 8; ++j){
            float v = Wcol[(size_t)(kf * 32 + l4 * 8 + j) * 256];
            u16 h = f2bf(v);
            hi8[j] = h;
            lo8[j] = f2bf(v - bf2f(h));
        }
        whi[kf] = __builtin_bit_cast(bf16x8, hi8);
        wlo[kf] = __builtin_bit_cast(bf16x8, lo8);
    }
    const int hc = (P0 >> 2) + l4;          // lane's h column
    const int grow = (g << 4) + l15;        // lane's global batch row
    const float* bx4[4] = {bgx, bix, bfx, box};
    const float* bh4[4] = {bgh, bih, bfh, boh};
    float bias[4];
    #pragma unroll
    for (int g2 = 0; g2 < 4; ++g2) bias[g2] = bx4[g2][hc] + bh4[g2][hc];
    float c_val = 0.f;
    if (ct0 > 0) c_val = c_ws[grow * 256 + hc];

    u32* greg = h32 + g * 8192;             // [2 slots][16 rows][256 cols] u32

    // ---- handshake: arrival + canary purity proof (+ watchdog) ----
    if (tid == 0){
        u32 ep = __hip_atomic_load(epochw, __ATOMIC_RELAXED, __HIP_MEMORY_SCOPE_AGENT);
        sh_epoch = ep;
        u32 base = 0x5AD00000u ^ (ep * 0x9E3779B1u) ^ ((u32)hsidx * 0x85EBCA6Bu);
        tstore1(canar + (g * 8 + nb) * 32, base + (u32)nb * 0x27220A95u, false);
        asm volatile("s_waitcnt vmcnt(0)");
        u32* arr = gready + ((u32)(hsidx & 1) * 16 + g) * 16;
        __hip_atomic_fetch_add(arr, 1u, __ATOMIC_RELAXED, __HIP_MEMORY_SCOPE_AGENT);
        u64 wd0 = __builtin_amdgcn_s_memrealtime();
        u32 v; int dead = 0;
        do {
            v = __hip_atomic_load(arr, __ATOMIC_RELAXED, __HIP_MEMORY_SCOPE_AGENT);
            if (__builtin_amdgcn_s_memrealtime() - wd0 > 2000000ull){ dead = 1; break; }
        } while ((v & 0xffu) < 8u);
        int pure = 1;
        if (!dead){
            for (int j = 0; j < 8; ++j){
                u32 c = tload1(canar + (g * 8 + j) * 32, false);
                if (c != base + (u32)j * 0x27220A95u) pure = 0;
            }
        }
        shflag = dead ? 2 : pure;
    }
    __syncthreads();
    const int mode = shflag;
    const u32 ep = sh_epoch;
    if (mode == 2) return;                  // fast-fail: visible absmax, no hang
    const bool icb = (mode == 0);

    // ---- first dispatch: clear own tag slice (kills poison false-matches),
    //      sequenced by phase-2 so no clear can land on a real t=0 store ----
    if (ct0 == 0){
        int s  = tid >> 8;                  // slot 0/1
        int rr = (tid >> 4) & 15;           // row 0..15
        int cc = (nb << 5) + ((tid & 15) << 1);
        tstore1(greg + s * 4096 + rr * 256 + cc,     0x0000FFFFu, icb);
        tstore1(greg + s * 4096 + rr * 256 + cc + 1, 0x0000FFFFu, icb);
        asm volatile("s_waitcnt vmcnt(0)");
        __syncthreads();
        if (tid == 0){
            u32* arr = gready + ((u32)(hsidx & 1) * 16 + g) * 16;
            __hip_atomic_fetch_add(arr, 0x100u, __ATOMIC_RELAXED, __HIP_MEMORY_SCOPE_AGENT);
            u64 wd0 = __builtin_amdgcn_s_memrealtime();
            u32 v;
            do {
                v = __hip_atomic_load(arr, __ATOMIC_RELAXED, __HIP_MEMORY_SCOPE_AGENT);
                if (__builtin_amdgcn_s_memrealtime() - wd0 > 2000000ull) break;
            } while (((v >> 8) & 0xffu) < 8u);
        }
        __syncthreads();
    }
    if (tid == 0)                           // arm word for dispatch hsidx+2
        __hip_atomic_store(gready + ((u32)((hsidx & 1) ^ 1) * 16 + g) * 16, 0u,
                           __ATOMIC_RELAXED, __HIP_MEMORY_SCOPE_AGENT);

    // ---- scan ----
    const u16* xgl = xg + (size_t)(g * 8 + nb) * steps * 2048
                        + (l15 << 7) + (w << 4) + (l4 << 2);
    const int prow = tid >> 5;              // poll identity: row 0..15
    const int pcol = (tid & 31) << 3;       // 8 cols
    const int tend = ct0 + steps;

    for (int t = ct0; t < tend; ++t){
        int tl = t - ct0;
        u16x4 xq = __builtin_nontemporal_load(
                       (const u16x4*)(xgl + (size_t)tl * 2048));
        f32x4 a0 = {0,0,0,0}, a1 = {0,0,0,0};
        if (t > 0){
            const int slot = (t - 1) & 1;
            const u32 tg = ((ep << 10) | (u32)(t - 1)) & 0xffffu;
            const bool icp = icb || (t == ct0);     // chunk boundary via IC
            const u32* pp = greg + slot * 4096 + prow * 256 + pcol;
            u32x4 qa = tload4(pp, icp), qb = tload4(pp + 4, icp);
            u64 wd0 = __builtin_amdgcn_s_memrealtime();
            for (;;){
                bool ok = ((qa[0]&0xffffu)==tg)&&((qa[1]&0xffffu)==tg)
                        &&((qa[2]&0xffffu)==tg)&&((qa[3]&0xffffu)==tg)
                        &&((qb[0]&0xffffu)==tg)&&((qb[1]&0xffffu)==tg)
                        &&((qb[2]&0xffffu)==tg)&&((qb[3]&0xffffu)==tg);
                if (!__ballot(!ok)) break;
                if (__builtin_amdgcn_s_memrealtime() - wd0 > 200000ull) break;
                if (icp) __builtin_amdgcn_s_sleep(1);
                qa = tload4(pp, icp); qb = tload4(pp + 4, icp);
            }
            u32 s0 = (qa[0] >> 16) | (qa[1] & 0xffff0000u);
            u32 s1 = (qa[2] >> 16) | (qa[3] & 0xffff0000u);
            u32 s2 = (qb[0] >> 16) | (qb[1] & 0xffff0000u);
            u32 s3 = (qb[2] >> 16) | (qb[3] & 0xffff0000u);
            *(u32x4*)(lds + slot * 8448 + prow * 528 + (pcol << 1))
                = (u32x4){s0, s1, s2, s3};
        }
        __syncthreads();
        if (t > 0){
            const int slot = (t - 1) & 1;
            const char* rb = lds + slot * 8448 + l15 * 528;
            #pragma unroll
            for (int kf = 0; kf < 8; ++kf){
                u16x8 hu = *(const u16x8*)(rb + (kf << 6) + (l4 << 4));
                bf16x8 hb = __builtin_bit_cast(bf16x8, hu);
                a0 = __builtin_amdgcn_mfma_f32_16x16x32_bf16(whi[kf], hb, a0, 0, 0, 0);
                a1 = __builtin_amdgcn_mfma_f32_16x16x32_bf16(wlo[kf], hb, a1, 0, 0, 0);
            }
        }
        float gs = bf2f(xq[0]) + bias[0] + a0[0] + a1[0];
        float is = bf2f(xq[1]) + bias[1] + a0[1] + a1[1];
        float fs = bf2f(xq[2]) + bias[2] + a0[2] + a1[2];
        float os = bf2f(xq[3]) + bias[3] + a0[3] + a1[3];
        float gv = tanhf_(gs);
        float iv = sigmoidf_(is);
        float fv = sigmoidf_(fs);
        float ov = sigmoidf_(os);
        c_val = gv * iv + c_val * fv;
        float hv = tanhf_(c_val) * ov;

        u32 hp = ((u32)f2bf(hv) << 16) | (((ep << 10) | (u32)t) & 0xffffu);
        tstore1(greg + (t & 1) * 4096 + l15 * 256 + hc, hp,
                icb || (t == tend - 1));    // last step via IC for next chunk
        if (t == 1023) hT[grow * 256 + hc] = hv;
    }
    if (tend < 1024) c_ws[grow * 256 + hc] = c_val;
}

// ---------------------------------------------------------------------------
// Kernel 3: p = hT @ Wph + bph; softmax over 10.
// ---------------------------------------------------------------------------
__global__ __launch_bounds__(256) void lstm_head(
    const float* __restrict__ hT, const float* __restrict__ Wph,
    const float* __restrict__ bph, float* __restrict__ out)
{
    int b = threadIdx.x;
    float p[10];
    #pragma unroll
    for (int j = 0; j < 10; ++j) p[j] = bph[j];
    const float* hr = hT + (b << 8);
    for (int k = 0; k < 256; ++k){
        float h = hr[k];
        const float* wr = Wph + k * 10;
        #pragma unroll
        for (int j = 0; j < 10; ++j) p[j] += h * wr[j];
    }
    float m = p[0];
    #pragma unroll
    for (int j = 1; j < 10; ++j) m = fmaxf(m, p[j]);
    float s = 0.f;
    #pragma unroll
    for (int j = 0; j < 10; ++j){ p[j] = __expf(p[j] - m); s += p[j]; }
    float inv = 1.f / s;
    #pragma unroll
    for (int j = 0; j < 10; ++j) out[b * 10 + j] = p[j] * inv;
}

// ---------------------------------------------------------------------------
extern "C" void kernel_launch(void* const* d_in, const int* in_sizes, int n_in,
                              void* d_out, int out_size, void* d_ws, size_t ws_size,
                              hipStream_t stream)
{
    const float* x   = (const float*)d_in[0];
    const float* Wgx = (const float*)d_in[1];  const float* bgx = (const float*)d_in[2];
    const float* Wgh = (const float*)d_in[3];  const float* bgh = (const float*)d_in[4];
    const float* Wix = (const float*)d_in[5];  const float* bix = (const float*)d_in[6];
    const float* Wih = (const float*)d_in[7];  const float* bih = (const float*)d_in[8];
    const float* Wfx = (const float*)d_in[9];  const float* bfx = (const float*)d_in[10];
    const float* Wfh = (const float*)d_in[11]; const float* bfh = (const float*)d_in[12];
    const float* Wox = (const float*)d_in[13]; const float* box = (const float*)d_in[14];
    const float* Woh = (const float*)d_in[15]; const float* boh = (const float*)d_in[16];
    const float* Wph = (const float*)d_in[17]; const float* bph = (const float*)d_in[18];
    float* out = (float*)d_out;

    char* ws = (char*)d_ws;
    u32*   h32    = (u32*)  (ws + 0);            // [16][2][4096] u32 = 512KB
    u32*   canar  = (u32*)  (ws + 524288);       // [16][8] lines = 16KB
    u32*   gready = (u32*)  (ws + 540672);       // 512 u32 (2 par x 16 g x 16)
    u32*   epochw = (u32*)  (ws + 542720);       // 1 u32 (+pad)
    float* cws    = (float*)(ws + 546816);       // [256][256] f32
    float* hT     = (float*)(ws + 808960);       // [256][256] f32
    u16*   Wxpt   = (u16*)  (ws + 1071104);      // [1024][128] bf16
    u16*   xgbuf  = (u16*)  (ws + 1333248);      // [128 blk][steps][2048] bf16
    size_t fixed = 1333248;
    size_t avail = ws_size > fixed ? ws_size - fixed : 0;
    long chunk = (long)(avail / 524288);         // 512KB per timestep
    if (chunk < 1) chunk = 1;
    if (chunk > 1024) chunk = 1024;

    lstm_pack<<<dim3(512), dim3(256), 0, stream>>>(Wgx, Wix, Wfx, Wox,
                                                   Wxpt, gready, epochw);
    int hsidx = 0;
    for (int ct0 = 0; ct0 < 1024; ct0 += (int)chunk){
        int steps = (int)((1024 - ct0 < chunk) ? (long)(1024 - ct0) : chunk);
        int mtiles = steps * 4;
        int mgroups = (mtiles + 15) / 16;
        lstm_xg<<<dim3(mgroups, 4), dim3(256), 0, stream>>>(
            x, Wxpt, xgbuf, ct0, steps, mtiles);
        lstm_rec<<<dim3(128), dim3(512), 0, stream>>>(
            xgbuf, Wgh, Wih, Wfh, Woh,
            bgx, bgh, bix, bih, bfx, bfh, box, boh,
            h32, canar, gready, epochw, cws, hT, ct0, steps, hsidx);
        ++hsidx;
    }
    lstm_head<<<dim3(1), dim3(256), 0, stream>>>(hT, Wph, bph, out);
}

// Round 8
// 7144.990 us; speedup vs baseline: 263.2266x; 263.2266x over previous
//
#include <hip/hip_runtime.h>

typedef unsigned short u16;
typedef unsigned u32;
typedef unsigned long long u64;
typedef __bf16 bf16x8 __attribute__((ext_vector_type(8)));
typedef u16 u16x8 __attribute__((ext_vector_type(8)));
typedef u16 u16x4 __attribute__((ext_vector_type(4)));
typedef float f32x4 __attribute__((ext_vector_type(4)));

__device__ __forceinline__ u16 f2bf(float f){
    unsigned u = __builtin_bit_cast(unsigned, f);
    u = (u + 0x7fffu + ((u >> 16) & 1u)) >> 16;
    return (u16)u;
}
__device__ __forceinline__ float bf2f(u16 h){
    unsigned u = ((unsigned)h) << 16;
    return __builtin_bit_cast(float, u);
}
__device__ __forceinline__ float sigmoidf_(float x){ return 1.0f / (1.0f + __expf(-x)); }
__device__ __forceinline__ float tanhf_(float x){
    float e = __expf(2.0f * x);
    return 1.0f - 2.0f / (e + 1.0f);
}

#define AL(p)   __hip_atomic_load((p), __ATOMIC_RELAXED, __HIP_MEMORY_SCOPE_AGENT)
#define AS(p,v) __hip_atomic_store((p),(v), __ATOMIC_RELAXED, __HIP_MEMORY_SCOPE_AGENT)
#define AA(p,v) __hip_atomic_fetch_add((p),(v), __ATOMIC_RELAXED, __HIP_MEMORY_SCOPE_AGENT)

// ---------------------------------------------------------------------------
// Kernel 0: pack Wx^T and Wh^T gate-interleaved bf16 (pk = 4*hcol + gate),
// pack bias (bx+bh) per pk, zero ring counters (segcnt[1024] + recprog[16]).
// ---------------------------------------------------------------------------
__global__ __launch_bounds__(256) void lstm_pack(
    const float* __restrict__ Wgx, const float* __restrict__ Wix,
    const float* __restrict__ Wfx, const float* __restrict__ Wox,
    const float* __restrict__ Wgh, const float* __restrict__ Wih,
    const float* __restrict__ Wfh, const float* __restrict__ Woh,
    const float* __restrict__ bgx, const float* __restrict__ bgh,
    const float* __restrict__ bix, const float* __restrict__ bih,
    const float* __restrict__ bfx, const float* __restrict__ bfh,
    const float* __restrict__ box, const float* __restrict__ boh,
    u16* __restrict__ Wxpt, u16* __restrict__ Whpt,
    float* __restrict__ biasp, u32* __restrict__ flags)
{
    int idx = blockIdx.x * 256 + threadIdx.x;   // 512 blocks -> 131072 threads
    if (idx < 1040) AS(flags + idx, 0u);
    const float* Wx4[4] = {Wgx, Wix, Wfx, Wox};
    const float* Wh4[4] = {Wgh, Wih, Wfh, Woh};
    if (idx < 131072){
        int pk = idx >> 7, k = idx & 127;
        Wxpt[idx] = f2bf(Wx4[pk & 3][k * 256 + (pk >> 2)]);
    }
    for (int o = idx; o < 262144; o += 131072){
        int pk = o >> 8, k = o & 255;
        Whpt[o] = f2bf(Wh4[pk & 3][k * 256 + (pk >> 2)]);
    }
    if (idx < 1024){
        const float* bx4[4] = {bgx, bix, bfx, box};
        const float* bh4[4] = {bgh, bih, bfh, boh};
        biasp[idx] = bx4[idx & 3][idx >> 2] + bh4[idx & 3][idx >> 2];
    }
}

// ---------------------------------------------------------------------------
// Kernel 1: fused producer/consumer.
//  blocks 0..15  : REC — block g owns batch rows [16g,16g+16) and ALL 1024 pk.
//                  Wh^T resident: 46 frags/lane in VGPR + 18 frags/wave in LDS.
//                  h lives in LDS (single 8KB buffer, 2 barriers/step).
//                  Consumes xg from the IC ring, 1 poll per segment.
//  blocks 16..143: PRODUCERS — producer p owns rows [16(p&15),..+16) and
//                  pk [128(p>>4),..+128); fills ring seg-by-seg; throttled by
//                  rec progress (ring depth 2). Bias folded into xg here.
// All cross-block traffic via __hip_atomic_* relaxed agent (IC-coherent,
// proven R2). No sc0 games, no XCD assumptions. Feed-forward only.
// ---------------------------------------------------------------------------
__global__ __launch_bounds__(512, 1) void lstm_fused(
    const float* __restrict__ x,
    const u16* __restrict__ Wxpt, const u16* __restrict__ Whpt,
    const float* __restrict__ biasp,
    u16* __restrict__ ring, u32* __restrict__ segcnt, u32* __restrict__ recprog,
    float* __restrict__ hT, int seg, int nseg)
{
    __shared__ char lds[155648];        // 8 waves x 18 W-frags x 1KB + 8KB h
    const int tid = threadIdx.x;
    const int w = tid >> 6, l = tid & 63;
    const int l15 = l & 15, l4 = l >> 4;
    const int bid = blockIdx.x;

    if (bid < 16){
        // ========================= REC =========================
        const int g = bid;
        char* WLDS = lds;               // [w][18][1024B]
        char* HLDS = lds + 147456;      // [16 rows][512B] bf16, rotated layout

        // ---- Wh^T fragments: f = tile*8+kf; f<46 -> VGPR, else LDS ----
        bf16x8 wv[46];
        #pragma unroll
        for (int f = 0; f < 46; ++f){
            int tile = f >> 3, kf = f & 7;
            int pkA = w * 128 + tile * 16 + l15;
            wv[f] = __builtin_bit_cast(bf16x8,
                *(const u16x8*)(Whpt + (size_t)pkA * 256 + kf * 32 + l4 * 8));
        }
        #pragma unroll
        for (int fl = 0; fl < 18; ++fl){
            int f = 46 + fl, tile = f >> 3, kf = f & 7;
            int pkA = w * 128 + tile * 16 + l15;
            u16x8 v = *(const u16x8*)(Whpt + (size_t)pkA * 256 + kf * 32 + l4 * 8);
            *(u16x8*)(WLDS + (w * 18 + fl) * 1024 + l * 16) = v;
        }
        float c[8];
        #pragma unroll
        for (int i = 0; i < 8; ++i) c[i] = 0.f;
        __syncthreads();

        bool gaveup = false;
        for (int s = 0; s < nseg; ++s){
            if (tid == 0 && !gaveup){                 // 1 poll / segment
                u64 wd = __builtin_amdgcn_s_memrealtime();
                while (AL(segcnt + s) < 128u){
                    if (__builtin_amdgcn_s_memrealtime() - wd > 50000000ull){
                        gaveup = true; break;         // proceed: loud garbage
                    }
                    __builtin_amdgcn_s_sleep(8);
                }
            }
            __syncthreads();                          // uniform: all proceed

            for (int tl = 0; tl < seg; ++tl){
                int t = s * seg + tl;
                // xg (bias included) for this lane's 8 tiles — IC loads
                const u16* xb = ring + ((size_t)((s & 1) * seg + tl)) * 262144
                              + (size_t)(g * 16 + l15) * 1024 + w * 128 + l4 * 4;
                u64 xq[8];
                #pragma unroll
                for (int i = 0; i < 8; ++i)
                    xq[i] = AL((const u64*)(xb + i * 16));

                bf16x8 hf[8];
                if (t > 0){
                    #pragma unroll
                    for (int kf = 0; kf < 8; ++kf){
                        int off = (kf * 64 + l4 * 16 + l15 * 32) & 511;
                        hf[kf] = __builtin_bit_cast(bf16x8,
                            *(const u16x8*)(HLDS + l15 * 512 + off));
                    }
                }
                __syncthreads();                      // B1: h reads done

                #pragma unroll
                for (int i = 0; i < 8; ++i){
                    f32x4 acc = {0.f, 0.f, 0.f, 0.f};
                    if (t > 0){
                        #pragma unroll
                        for (int kf = 0; kf < 8; ++kf){
                            int f = i * 8 + kf;
                            bf16x8 wa;
                            if (f < 46) wa = wv[f];
                            else wa = __builtin_bit_cast(bf16x8,
                                *(const u16x8*)(WLDS + (w * 18 + (f - 46)) * 1024 + l * 16));
                            acc = __builtin_amdgcn_mfma_f32_16x16x32_bf16(wa, hf[kf], acc, 0, 0, 0);
                        }
                    }
                    u16x4 x4 = __builtin_bit_cast(u16x4, xq[i]);
                    float gv = tanhf_(bf2f(x4[0]) + acc[0]);
                    float iv = sigmoidf_(bf2f(x4[1]) + acc[1]);
                    float fv = sigmoidf_(bf2f(x4[2]) + acc[2]);
                    float ov = sigmoidf_(bf2f(x4[3]) + acc[3]);
                    c[i] = gv * iv + c[i] * fv;
                    float hv = tanhf_(c[i]) * ov;
                    int hcol = w * 32 + i * 4 + l4;
                    *(u16*)(HLDS + l15 * 512 + ((hcol * 2 + l15 * 32) & 511)) = f2bf(hv);
                    if (t == 1023) hT[(size_t)(g * 16 + l15) * 256 + hcol] = hv;
                }
                __syncthreads();                      // B2: h writes done
            }
            if (tid == 0) AS(recprog + g, (u32)(s + 1));
        }
        if (gaveup && tid == 0)                       // decisive poison
            for (int j = 0; j < 256; ++j) hT[(size_t)(g * 16) * 256 + j] = 1e30f;
    } else {
        // ====================== PRODUCER =======================
        const int p = bid - 16;
        const int pr = p & 15, pc = p >> 4;
        const int n0 = pc * 128;                      // pk slice base
        u16* Bt = (u16*)lds;                          // 32KB Wx tile, swizzled
        for (int ii = 0; ii < 4; ++ii){
            int cid = ii * 512 + tid;
            int nn = cid >> 4, kc = (cid & 15) << 3;
            u16x8 v = *(const u16x8*)(Wxpt + (size_t)(n0 + nn) * 128 + kc);
            u32 byte = ((u32)(nn << 8) + (u32)(kc << 1)) ^ ((u32)(nn & 7) << 4);
            *(u16x8*)((char*)Bt + byte) = v;
        }
        __syncthreads();
        const int b = pr * 16 + l15;                  // batch row
        const int pkg = n0 + w * 16 + l4 * 4;         // lane's 4 pk
        const f32x4 bias4 = *(const f32x4*)(biasp + pkg);
        const float* xr = x + (size_t)b * 1024 * 128;
        const int nnA = w * 16 + l15;
        bool gaveup = false;

        for (int s = 0; s < nseg; ++s){
            if (s >= 2 && tid == 0 && !gaveup){       // ring-reuse throttle
                u64 wd = __builtin_amdgcn_s_memrealtime();
                for (;;){
                    u32 mn = 0xffffffffu;
                    for (int j = 0; j < 16; ++j){
                        u32 v = AL(recprog + j);
                        mn = v < mn ? v : mn;
                    }
                    if ((int)mn >= s - 1) break;
                    if (__builtin_amdgcn_s_memrealtime() - wd > 50000000ull){
                        gaveup = true; break;
                    }
                    __builtin_amdgcn_s_sleep(32);
                }
            }
            __syncthreads();                          // uniform proceed

            for (int tl = 0; tl < seg; ++tl){
                int t = s * seg + tl;
                f32x4 acc = {0.f, 0.f, 0.f, 0.f};
                #pragma unroll
                for (int kf = 0; kf < 4; ++kf){
                    int k0 = kf * 32 + l4 * 8;
                    f32x4 xa = *(const f32x4*)(xr + (size_t)t * 128 + k0);
                    f32x4 xc = *(const f32x4*)(xr + (size_t)t * 128 + k0 + 4);
                    u16x8 bu;
                    bu[0]=f2bf(xa[0]); bu[1]=f2bf(xa[1]); bu[2]=f2bf(xa[2]); bu[3]=f2bf(xa[3]);
                    bu[4]=f2bf(xc[0]); bu[5]=f2bf(xc[1]); bu[6]=f2bf(xc[2]); bu[7]=f2bf(xc[3]);
                    u32 byte = ((u32)(nnA << 8) + (u32)(k0 << 1)) ^ ((u32)(nnA & 7) << 4);
                    bf16x8 af = __builtin_bit_cast(bf16x8, *(const u16x8*)((const char*)Bt + byte));
                    acc = __builtin_amdgcn_mfma_f32_16x16x32_bf16(
                              af, __builtin_bit_cast(bf16x8, bu), acc, 0, 0, 0);
                }
                acc += bias4;                          // fold bias into xg
                u16x4 o;
                o[0]=f2bf(acc[0]); o[1]=f2bf(acc[1]); o[2]=f2bf(acc[2]); o[3]=f2bf(acc[3]);
                size_t ridx = ((size_t)((s & 1) * seg + tl)) * 262144
                            + (size_t)b * 1024 + pkg;
                AS((u64*)(ring + ridx), __builtin_bit_cast(u64, o));
            }
            __syncthreads();                          // vmcnt(0): stores at IC
            if (tid == 0) AA(segcnt + s, 1u);         // publish segment
        }
    }
}

// ---------------------------------------------------------------------------
// Kernel 2: p = hT @ Wph + bph; softmax over 10.
// ---------------------------------------------------------------------------
__global__ __launch_bounds__(256) void lstm_head(
    const float* __restrict__ hT, const float* __restrict__ Wph,
    const float* __restrict__ bph, float* __restrict__ out)
{
    int b = threadIdx.x;
    float p[10];
    #pragma unroll
    for (int j = 0; j < 10; ++j) p[j] = bph[j];
    const float* hr = hT + (size_t)b * 256;
    for (int k = 0; k < 256; ++k){
        float h = hr[k];
        const float* wr = Wph + k * 10;
        #pragma unroll
        for (int j = 0; j < 10; ++j) p[j] += h * wr[j];
    }
    float m = p[0];
    #pragma unroll
    for (int j = 1; j < 10; ++j) m = fmaxf(m, p[j]);
    float s = 0.f;
    #pragma unroll
    for (int j = 0; j < 10; ++j){ p[j] = __expf(p[j] - m); s += p[j]; }
    float inv = 1.f / s;
    #pragma unroll
    for (int j = 0; j < 10; ++j) out[b * 10 + j] = p[j] * inv;
}

// ---------------------------------------------------------------------------
extern "C" void kernel_launch(void* const* d_in, const int* in_sizes, int n_in,
                              void* d_out, int out_size, void* d_ws, size_t ws_size,
                              hipStream_t stream)
{
    const float* x   = (const float*)d_in[0];
    const float* Wgx = (const float*)d_in[1];  const float* bgx = (const float*)d_in[2];
    const float* Wgh = (const float*)d_in[3];  const float* bgh = (const float*)d_in[4];
    const float* Wix = (const float*)d_in[5];  const float* bix = (const float*)d_in[6];
    const float* Wih = (const float*)d_in[7];  const float* bih = (const float*)d_in[8];
    const float* Wfx = (const float*)d_in[9];  const float* bfx = (const float*)d_in[10];
    const float* Wfh = (const float*)d_in[11]; const float* bfh = (const float*)d_in[12];
    const float* Wox = (const float*)d_in[13]; const float* box = (const float*)d_in[14];
    const float* Woh = (const float*)d_in[15]; const float* boh = (const float*)d_in[16];
    const float* Wph = (const float*)d_in[17]; const float* bph = (const float*)d_in[18];
    float* out = (float*)d_out;

    char* ws = (char*)d_ws;
    u32*   flags = (u32*)  (ws + 0);         // segcnt[1024] + recprog[16]
    float* hT    = (float*)(ws + 8192);      // 256KB -> 270336
    u16*   Whpt  = (u16*)  (ws + 270336);    // 512KB -> 794624
    u16*   Wxpt  = (u16*)  (ws + 794624);    // 256KB -> 1056768
    float* biasp = (float*)(ws + 1056768);   // 4KB   -> 1060864
    u16*   ring  = (u16*)  (ws + 1060864);   // 2 x seg x 512KB

    size_t avail = ws_size > 1060864 ? ws_size - 1060864 : 0;
    int seg = 8;
    while (seg > 1 && (size_t)seg * 1048576 > avail) seg >>= 1;
    int nseg = 1024 / seg;

    lstm_pack<<<dim3(512), dim3(256), 0, stream>>>(
        Wgx, Wix, Wfx, Wox, Wgh, Wih, Wfh, Woh,
        bgx, bgh, bix, bih, bfx, bfh, box, boh,
        Wxpt, Whpt, biasp, flags);
    lstm_fused<<<dim3(144), dim3(512), 0, stream>>>(
        x, Wxpt, Whpt, biasp, ring, flags, flags + 1024, hT, seg, nseg);
    lstm_head<<<dim3(1), dim3(256), 0, stream>>>(hT, Wph, bph, out);
}